// Round 6
// baseline (396.812 us; speedup 1.0000x reference)
//
#include <hip/hip_runtime.h>
#include <hip/hip_bf16.h>

// ---------------------------------------------------------------------------
// ramsey_NN: node MLP (3 layers, train-mode BN) + all-pairs edge head.
// N=2048, F=64, H=128, C=2.  E = N(N-1)/2 = 2096128.
//
// R6 = R5 with the edge_p2 cross-wave reduction bug fixed:
//   R5 raced: each wave wrote sigmoid(its 32-of-128 h partial) to the same
//   location. R6: per-wave partials -> sV[w][i][j] (single writer per slot,
//   no atomics), one barrier, coalesced final sum+sigmoid+write.
//   Everything else as R5:
//   * edge_p2: dpAll[4][8] register accumulation, packed float2 fma epilogue.
//   * edge_p1: packed {Sz,S|z|,Qzz,Qz|z|} stats, zero barriers, wave-tail
//     atomics to per-XCD SQe8 (lrelu reconstructed: a=.505z+.495|z|,
//     a^2=.50005 z^2+.49995 z|z|).
//   * k_mid separate; k_l3 + k_bi(2048 blocks); W5->bf16 fused into k_l1.
// ---------------------------------------------------------------------------

typedef short short8 __attribute__((ext_vector_type(8)));   // 8 x bf16
typedef float floatx4 __attribute__((ext_vector_type(4)));  // MFMA C/D
typedef float float2v __attribute__((ext_vector_type(2)));  // packed f32 pair

#define NN 2048
#define EPSV 1e-5f
#define EDGEF 2096128.f

__device__ __forceinline__ float bf2f(short s) {
    return __uint_as_float(((unsigned)(unsigned short)s) << 16);
}
__device__ __forceinline__ short f2bf(float f) {   // RNE
    unsigned u = __float_as_uint(f);
    unsigned r = (u + 0x7FFFu + ((u >> 16) & 1u)) >> 16;
    return (short)r;
}
__device__ __forceinline__ float lrelu(float x) { return fmaxf(x, 0.01f * x); }
__device__ __forceinline__ float2v absv(float2v x) {
    float2v r; r.x = __builtin_fabsf(x.x); r.y = __builtin_fabsf(x.y); return r;
}
__device__ __forceinline__ float2v fma2(float2v a, float2v b, float2v c) {
    float2v r; r.x = fmaf(a.x, b.x, c.x); r.y = fmaf(a.y, b.y, c.y); return r;
}

// fragment-physical chunk index (16x16x32 bf16, A/B identity layout)
__device__ __forceinline__ int physB(int h, int f) {
    return ((((h >> 4) * 2 + (f >> 5)) * 64 + ((f >> 3) & 3) * 16 + (h & 15)) * 8) + (f & 7);
}

// 1-D active-tile decode: rows-of-8 nodes, j-tiles of 64.
// Row ig8 pinned to XCD ig8%8 (blockIdx%8 round-robin heuristic).
// Per-XCD slots: sum_{m=0}^{31}(32-m)=528; grid = 4224.
__device__ __forceinline__ void decode_tile(int bid, int& i0, int& j0, bool& str) {
    int s = bid >> 3, m = 0;
#pragma unroll 1
    while (s >= 32 - m) { s -= 32 - m; ++m; }
    i0 = ((bid & 7) + (m << 3)) * 8;
    j0 = (m + s) * 64;
    str = (s == 0);
}

// ---------------- node layer 1 (+ W5->bf16 conversion on blocks 0..31) -------
__global__ __launch_bounds__(256) void k_l1(const float* __restrict__ nf,
                                            const float* __restrict__ W1,
                                            const float* __restrict__ b1,
                                            const float* __restrict__ W5,
                                            float* __restrict__ act1,
                                            float* __restrict__ stat1,
                                            short* __restrict__ w5bf) {
    __shared__ float xl[8 * 64];
    __shared__ float sS[128], sQ[128];
    int t = threadIdx.x, n0 = blockIdx.x * 8;
    if (blockIdx.x < 32) {                     // fused W5 -> bf16 frag-physical
        int idx = blockIdx.x * 256 + t;        // f*128+h over 8192
        w5bf[physB(idx & 127, idx >> 7)] = f2bf(W5[idx]);
    }
    if (t < 128) { sS[t] = 0.f; sQ[t] = 0.f; }
    xl[t] = nf[(size_t)n0 * 64 + t];
    xl[t + 256] = nf[(size_t)n0 * 64 + t + 256];
    __syncthreads();
    int nl = t >> 5, h0 = (t & 31) * 4;
    float acc[4];
    for (int k = 0; k < 4; ++k) acc[k] = b1[h0 + k];
    for (int f = 0; f < 64; ++f) {
        float r = xl[nl * 64 + f];
        const float* wr = W1 + f * 128 + h0;
        for (int k = 0; k < 4; ++k) acc[k] = fmaf(r, wr[k], acc[k]);
    }
    for (int k = 0; k < 4; ++k) {
        float a = lrelu(acc[k]);
        act1[(size_t)(n0 + nl) * 128 + h0 + k] = a;
        atomicAdd(&sS[h0 + k], a);
        atomicAdd(&sQ[h0 + k], a * a);
    }
    __syncthreads();
    if (t < 128) atomicAdd(&stat1[t], sS[t]);
    else atomicAdd(&stat1[t], sQ[t - 128]);
}

// ---------------- node layer 2 ----------------------------------------------
__global__ __launch_bounds__(256) void k_l2(const float* __restrict__ act1,
                                            const float* __restrict__ stat1,
                                            const float* __restrict__ g1,
                                            const float* __restrict__ be1,
                                            const float* __restrict__ W2,
                                            const float* __restrict__ b2,
                                            float* __restrict__ act2,
                                            float* __restrict__ stat2) {
    __shared__ float a1n[8 * 128];
    __shared__ float sS[128], sQ[128];
    int t = threadIdx.x, n0 = blockIdx.x * 8;
    if (t < 128) { sS[t] = 0.f; sQ[t] = 0.f; }
    for (int k = 0; k < 4; ++k) {
        int e = t + 256 * k;
        int nl = e >> 7, h = e & 127;
        float m = stat1[h] * (1.f / 2048.f);
        float v = stat1[128 + h] * (1.f / 2048.f) - m * m;
        float sc = rsqrtf(v + EPSV);
        a1n[e] = (act1[(size_t)(n0 + nl) * 128 + h] - m) * sc * g1[h] + be1[h];
    }
    __syncthreads();
    int nl = t >> 5, h0 = (t & 31) * 4;
    float acc[4];
    for (int k = 0; k < 4; ++k) acc[k] = b2[h0 + k];
    for (int hi = 0; hi < 128; ++hi) {
        float r = a1n[nl * 128 + hi];
        const float* wr = W2 + hi * 128 + h0;
        for (int k = 0; k < 4; ++k) acc[k] = fmaf(r, wr[k], acc[k]);
    }
    for (int k = 0; k < 4; ++k) {
        float a = lrelu(acc[k]);
        act2[(size_t)(n0 + nl) * 128 + h0 + k] = a;
        atomicAdd(&sS[h0 + k], a);
        atomicAdd(&sQ[h0 + k], a * a);
    }
    __syncthreads();
    if (t < 128) atomicAdd(&stat2[t], sS[t]);
    else atomicAdd(&stat2[t], sQ[t - 128]);
}

// ---------------- node layer 3 + residual -> hb (bf16) -----------------------
__global__ __launch_bounds__(256) void k_l3(const float* __restrict__ act2,
                                            const float* __restrict__ stat2,
                                            const float* __restrict__ g2,
                                            const float* __restrict__ be2,
                                            const float* __restrict__ W3,
                                            const float* __restrict__ b3,
                                            const float* __restrict__ nf,
                                            short* __restrict__ hb) {
    __shared__ float a2n[8 * 128];
    int t = threadIdx.x, n0 = blockIdx.x * 8;
    for (int k = 0; k < 4; ++k) {
        int e = t + 256 * k;
        int nl = e >> 7, h = e & 127;
        float m = stat2[h] * (1.f / 2048.f);
        float v = stat2[128 + h] * (1.f / 2048.f) - m * m;
        float sc = rsqrtf(v + EPSV);
        a2n[e] = (act2[(size_t)(n0 + nl) * 128 + h] - m) * sc * g2[h] + be2[h];
    }
    __syncthreads();
    int nl = t >> 5, f0 = (t & 31) * 2;
    float acc[2] = {0.f, 0.f};
    for (int hi = 0; hi < 128; ++hi) {
        float r = a2n[nl * 128 + hi];
        const float* wr = W3 + hi * 64 + f0;
        acc[0] = fmaf(r, wr[0], acc[0]);
        acc[1] = fmaf(r, wr[1], acc[1]);
    }
    float v0 = acc[0] + b3[f0] + nf[(size_t)(n0 + nl) * 64 + f0];
    float v1 = acc[1] + b3[f0 + 1] + nf[(size_t)(n0 + nl) * 64 + f0 + 1];
    unsigned p = (unsigned)(unsigned short)f2bf(v0) |
                 ((unsigned)(unsigned short)f2bf(v1) << 16);
    ((unsigned*)hb)[(size_t)(n0 + nl) * 32 + (f0 >> 1)] = p;
}

// ---------------- T[i] = diag(h_i) @ W5, fragment-physical (2048 blocks) -----
__global__ __launch_bounds__(256) void k_bi(const short* __restrict__ w5bf,
                                            const short* __restrict__ hb,
                                            short* __restrict__ T) {
    int i = blockIdx.x, t = threadIdx.x;
    __shared__ short sHi[64];
    if (t < 8) ((short8*)sHi)[t] = ((const short8*)(hb + (size_t)i * 64))[t];
    __syncthreads();
#pragma unroll
    for (int k = 0; k < 4; ++k) {
        int c = t + 256 * k;                 // chunk 0..1023
        int ks = (c >> 6) & 1, quad = (c & 63) >> 4;
        int fb = ks * 32 + quad * 8;
        short8 wv = ((const short8*)w5bf)[c];
        short8 hv = *(const short8*)(sHi + fb);
        short8 ov;
#pragma unroll
        for (int e = 0; e < 8; ++e) ov[e] = f2bf(bf2f(wv[e]) * bf2f(hv[e]));
        ((short8*)(T + (size_t)i * 8192))[c] = ov;
    }
}

// ---------------- BN+softmax fold (1 block) ----------------------------------
__global__ void k_mid(const float* __restrict__ SQe8, const float* __restrict__ W6,
                      const float* __restrict__ b6, const float* __restrict__ g5,
                      const float* __restrict__ be5, float* __restrict__ w6d,
                      float* __restrict__ b6d) {
    __shared__ float part[128];
    int h = threadIdx.x;
    float s = 0.f, q = 0.f;
    for (int x = 0; x < 8; ++x) {
        s += SQe8[x * 256 + h];
        q += SQe8[x * 256 + 128 + h];
    }
    float m = s / EDGEF;
    float v = q / EDGEF - m * m;
    float sc = rsqrtf(v + EPSV);
    float dW = W6[h * 2] - W6[h * 2 + 1];
    float sg = sc * g5[h];
    w6d[h] = sg * dW;
    part[h] = (be5[h] - m * sg) * dW;
    __syncthreads();
    if (h == 0) {
        float acc = b6[0] - b6[1];
        for (int k = 0; k < 128; ++k) acc += part[k];
        b6d[0] = acc;
    }
}

// ---------------- edge pass 1: BN stats (zero barriers) ----------------------
__global__ __launch_bounds__(256) void edge_p1(
    const short* __restrict__ hb, const short* __restrict__ T,
    const float* __restrict__ b5, float* __restrict__ SQe8)
{
    int i0, j0; bool str;
    decode_tile(blockIdx.x, i0, j0, str);

    int t = threadIdx.x, lane = t & 63, w = t >> 6;
    int quad = lane >> 4, col = lane & 15;

    short8 hfr[4][2];
#pragma unroll
    for (int mt = 0; mt < 4; ++mt)
#pragma unroll
        for (int ks = 0; ks < 2; ++ks)
            hfr[mt][ks] = *(const short8*)(hb + (size_t)(j0 + mt * 16 + col) * 64 + ks * 32 + quad * 8);

    const short* Tb = T + (size_t)i0 * 8192;
    int toff[2][2];
#pragma unroll
    for (int n = 0; n < 2; ++n)
#pragma unroll
        for (int ks = 0; ks < 2; ++ks)
            toff[n][ks] = ((((w * 2 + n) * 2 + ks) * 64) + lane) * 8;

    float b5c[2] = { b5[w * 32 + col], b5[w * 32 + 16 + col] };
    float2v Sz[2], Su[2], Qzz[2], Qzu[2];
#pragma unroll
    for (int n = 0; n < 2; ++n) {
        Sz[n] = 0.f; Su[n] = 0.f; Qzz[n] = 0.f; Qzu[n] = 0.f;
    }

    short8 ta[2][2], tb[2][2];
#pragma unroll
    for (int n = 0; n < 2; ++n)
#pragma unroll
        for (int ks = 0; ks < 2; ++ks)
            ta[n][ks] = *(const short8*)(Tb + toff[n][ks]);

    auto body1 = [&](int i, short8 (&tc)[2][2]) {
        int igi = i0 + i;
#pragma unroll
        for (int n = 0; n < 2; ++n) {
#pragma unroll
            for (int mt = 0; mt < 4; ++mt) {
                floatx4 c = {b5c[n], b5c[n], b5c[n], b5c[n]};
                c = __builtin_amdgcn_mfma_f32_16x16x32_bf16(hfr[mt][0], tc[n][0], c, 0, 0, 0);
                c = __builtin_amdgcn_mfma_f32_16x16x32_bf16(hfr[mt][1], tc[n][1], c, 0, 0, 0);
                float2v z01, z23;
                if (!str) {
                    z01.x = c[0]; z01.y = c[1];
                    z23.x = c[2]; z23.y = c[3];
                } else {
                    int jb = j0 + mt * 16 + quad * 4;
                    z01.x = (jb + 0 > igi) ? c[0] : 0.f;
                    z01.y = (jb + 1 > igi) ? c[1] : 0.f;
                    z23.x = (jb + 2 > igi) ? c[2] : 0.f;
                    z23.y = (jb + 3 > igi) ? c[3] : 0.f;
                }
                float2v u01 = absv(z01), u23 = absv(z23);
                Sz[n] += z01 + z23;
                Su[n] += u01 + u23;
                Qzz[n] = fma2(z01, z01, Qzz[n]);
                Qzz[n] = fma2(z23, z23, Qzz[n]);
                Qzu[n] = fma2(z01, u01, Qzu[n]);
                Qzu[n] = fma2(z23, u23, Qzu[n]);
            }
        }
    };

    for (int ii = 0; ii < 8; ii += 2) {
        {
            const short* Tn = Tb + (size_t)(ii + 1) * 8192;
#pragma unroll
            for (int n = 0; n < 2; ++n)
#pragma unroll
                for (int ks = 0; ks < 2; ++ks)
                    tb[n][ks] = *(const short8*)(Tn + toff[n][ks]);
        }
        body1(ii, ta);
        if (ii + 2 < 8) {
            const short* Tn = Tb + (size_t)(ii + 2) * 8192;
#pragma unroll
            for (int n = 0; n < 2; ++n)
#pragma unroll
                for (int ks = 0; ks < 2; ++ks)
                    ta[n][ks] = *(const short8*)(Tn + toff[n][ks]);
        }
        body1(ii + 1, tb);
    }

    float* dst = SQe8 + (blockIdx.x & 7) * 256;
#pragma unroll
    for (int n = 0; n < 2; ++n) {
        // a = lrelu(z) = .505 z + .495|z|;  a^2 = .50005 z^2 + .49995 z|z|
        float Sa = 0.505f * (Sz[n].x + Sz[n].y) + 0.495f * (Su[n].x + Su[n].y);
        float Qa = 0.50005f * (Qzz[n].x + Qzz[n].y) + 0.49995f * (Qzu[n].x + Qzu[n].y);
        Sa += __shfl_xor(Sa, 16); Sa += __shfl_xor(Sa, 32);
        Qa += __shfl_xor(Qa, 16); Qa += __shfl_xor(Qa, 32);
        if (quad == 0) {
            atomicAdd(&dst[w * 32 + n * 16 + col], Sa);
            atomicAdd(&dst[128 + w * 32 + n * 16 + col], Qa);
        }
    }
}

// ---------------- edge pass 2: probabilities + symmetric write ---------------
__global__ __launch_bounds__(256) void edge_p2(
    const short* __restrict__ hb, const short* __restrict__ T,
    const float* __restrict__ b5, const float* __restrict__ w6d,
    const float* __restrict__ b6dp, float* __restrict__ out)
{
    int i0, j0; bool str;
    decode_tile(blockIdx.x, i0, j0, str);
    __shared__ float sV[4][8][64];    // per-wave partial h-sums (8 KB)
    __shared__ float sP[8][65];       // probs, padded (mirror transpose)

    int t = threadIdx.x, lane = t & 63, w = t >> 6;
    int quad = lane >> 4, col = lane & 15;

    float bb = b6dp[0];
    float b5q[2][4];
    float2v wa2[2][2], wb2[2][2];
#pragma unroll
    for (int m = 0; m < 2; ++m)
#pragma unroll
        for (int r = 0; r < 4; ++r) {
            int h = w * 32 + m * 16 + quad * 4 + r;
            b5q[m][r] = b5[h];
            float wd = w6d[h];
            ((float*)&wa2[m][r >> 1])[r & 1] = 0.505f * wd;
            ((float*)&wb2[m][r >> 1])[r & 1] = 0.495f * wd;
        }

    short8 hfr[4][2];
#pragma unroll
    for (int mt = 0; mt < 4; ++mt)
#pragma unroll
        for (int ks = 0; ks < 2; ++ks)
            hfr[mt][ks] = *(const short8*)(hb + (size_t)(j0 + mt * 16 + col) * 64 + ks * 32 + quad * 8);

    const short* Tb = T + (size_t)i0 * 8192;
    int toff[2][2];
#pragma unroll
    for (int m = 0; m < 2; ++m)
#pragma unroll
        for (int ks = 0; ks < 2; ++ks)
            toff[m][ks] = ((((w * 2 + m) * 2 + ks) * 64) + lane) * 8;

    short8 ta[2][2], tb[2][2];
#pragma unroll
    for (int m = 0; m < 2; ++m)
#pragma unroll
        for (int ks = 0; ks < 2; ++ks)
            ta[m][ks] = *(const short8*)(Tb + toff[m][ks]);

    float dpAll[4][8];                // [nj][i] per-wave register accumulation

    auto body2 = [&](int i, short8 (&tc)[2][2]) {
        float2v acc[4];
#pragma unroll
        for (int k = 0; k < 4; ++k) acc[k] = 0.f;
#pragma unroll
        for (int m = 0; m < 2; ++m) {
#pragma unroll
            for (int nj = 0; nj < 4; ++nj) {
                floatx4 c = {b5q[m][0], b5q[m][1], b5q[m][2], b5q[m][3]};
                c = __builtin_amdgcn_mfma_f32_16x16x32_bf16(tc[m][0], hfr[nj][0], c, 0, 0, 0);
                c = __builtin_amdgcn_mfma_f32_16x16x32_bf16(tc[m][1], hfr[nj][1], c, 0, 0, 0);
                float2v z01, z23;
                z01.x = c[0]; z01.y = c[1];
                z23.x = c[2]; z23.y = c[3];
                float2v u01 = absv(z01), u23 = absv(z23);
                acc[nj] = fma2(z01, wa2[m][0], acc[nj]);
                acc[nj] = fma2(u01, wb2[m][0], acc[nj]);
                acc[nj] = fma2(z23, wa2[m][1], acc[nj]);
                acc[nj] = fma2(u23, wb2[m][1], acc[nj]);
            }
        }
#pragma unroll
        for (int nj = 0; nj < 4; ++nj) dpAll[nj][i] = acc[nj].x + acc[nj].y;
    };

    for (int ii = 0; ii < 8; ii += 2) {
        {
            const short* Tn = Tb + (size_t)(ii + 1) * 8192;
#pragma unroll
            for (int m = 0; m < 2; ++m)
#pragma unroll
                for (int ks = 0; ks < 2; ++ks)
                    tb[m][ks] = *(const short8*)(Tn + toff[m][ks]);
        }
        body2(ii, ta);
        if (ii + 2 < 8) {
            const short* Tn = Tb + (size_t)(ii + 2) * 8192;
#pragma unroll
            for (int m = 0; m < 2; ++m)
#pragma unroll
                for (int ks = 0; ks < 2; ++ks)
                    ta[m][ks] = *(const short8*)(Tn + toff[m][ks]);
        }
        body2(ii + 1, tb);
    }

    // deferred tail 1: quad-butterfly, single writer per sV slot (no atomics)
#pragma unroll
    for (int i = 0; i < 8; ++i) {
#pragma unroll
        for (int nj = 0; nj < 4; ++nj) {
            float v = dpAll[nj][i];
            v += __shfl_xor(v, 16);
            v += __shfl_xor(v, 32);
            if (quad == (i & 3)) sV[w][i][nj * 16 + col] = v;
        }
    }
    __syncthreads();

    // deferred tail 2: cross-wave sum + sigmoid + direct write (coalesced)
#pragma unroll
    for (int k = 0; k < 2; ++k) {
        int e = t + 256 * k;          // 0..511
        int il = e >> 6, jl = e & 63;
        float v = bb + sV[0][il][jl] + sV[1][il][jl] + sV[2][il][jl] + sV[3][il][jl];
        float p = 1.f / (1.f + __expf(-v));
        sP[il][jl] = p;
        int ig = i0 + il, jg = j0 + jl;
        float2v pr;
        if (!str || jg > ig) {
            pr.x = p; pr.y = 1.f - p;
            *(float2v*)(out + ((size_t)ig * NN + jg) * 2) = pr;
        } else if (jg == ig) {
            pr.x = 0.f; pr.y = 0.f;
            *(float2v*)(out + ((size_t)ig * NN + jg) * 2) = pr;
        }
    }
    __syncthreads();

    if (!str) {
        // mirror: 64 rows x 16 floats, float4 per thread
        int jr = t >> 2, f1 = (t & 3) * 4;
        float4 u;
#pragma unroll
        for (int e = 0; e < 4; ++e) {
            int ff = f1 + e;
            float p = sP[ff >> 1][jr];
            ((float*)&u)[e] = (ff & 1) ? 1.f - p : p;
        }
        *(float4*)(out + ((size_t)(j0 + jr) * NN + i0) * 2 + f1) = u;
    } else {
#pragma unroll
        for (int e = 0; e < 4; ++e) {     // mirror 64x8x2 = 1024 floats
            int f = t * 4 + e;
            int jr = f >> 4, ff = f & 15;
            int il = ff >> 1, c2 = ff & 1;
            int jg = j0 + jr, ig = i0 + il;
            if (jg > ig) {
                float p = sP[il][jr];
                out[((size_t)jg * NN + ig) * 2 + c2] = c2 ? 1.f - p : p;
            }
        }
    }
}

// ---------------------------------------------------------------------------
extern "C" void kernel_launch(void* const* d_in, const int* in_sizes, int n_in,
                              void* d_out, int out_size, void* d_ws, size_t ws_size,
                              hipStream_t stream) {
    const float* nf  = (const float*)d_in[1];   // d_in[0]=x unused (ref ignores it)
    const float* W1  = (const float*)d_in[2];
    const float* b1  = (const float*)d_in[3];
    const float* g1  = (const float*)d_in[4];
    const float* be1 = (const float*)d_in[5];
    const float* W2  = (const float*)d_in[6];
    const float* b2  = (const float*)d_in[7];
    const float* g2  = (const float*)d_in[8];
    const float* be2 = (const float*)d_in[9];
    const float* W3  = (const float*)d_in[10];
    const float* b3  = (const float*)d_in[11];
    const float* W5  = (const float*)d_in[12];
    const float* b5  = (const float*)d_in[13];
    const float* g5  = (const float*)d_in[14];
    const float* be5 = (const float*)d_in[15];
    const float* W6  = (const float*)d_in[16];
    const float* b6  = (const float*)d_in[17];
    float* out = (float*)d_out;

    float* wsf   = (float*)d_ws;
    float* stat1 = wsf;                 // 256
    float* stat2 = wsf + 256;           // 256
    float* SQe8  = wsf + 512;           // 8*256 = 2048 (per-XCD stat copies)
    float* w6d   = wsf + 2560;          // 128
    float* b6dp  = wsf + 2688;          // 1 (pad to 4096)
    float* act1  = wsf + 4096;          // 262144
    float* act2  = act1 + 262144;       // 262144
    short* hb    = (short*)(act2 + 262144);   // 131072 bf16
    short* w5bf  = hb + 131072;               // 8192 bf16
    short* Tbuf  = w5bf + 8192;               // 2048*8192 bf16 = 32 MB

    hipMemsetAsync(d_ws, 0, 4096 * sizeof(float), stream);

    k_l1<<<256, 256, 0, stream>>>(nf, W1, b1, W5, act1, stat1, w5bf);
    k_l2<<<256, 256, 0, stream>>>(act1, stat1, g1, be1, W2, b2, act2, stat2);
    k_l3<<<256, 256, 0, stream>>>(act2, stat2, g2, be2, W3, b3, nf, hb);
    k_bi<<<2048, 256, 0, stream>>>(w5bf, hb, Tbuf);

    edge_p1<<<4224, 256, 0, stream>>>(hb, Tbuf, b5, SQe8);
    k_mid<<<1, 128, 0, stream>>>(SQe8, W6, b6, g5, be5, w6d, b6dp);
    edge_p2<<<4224, 256, 0, stream>>>(hb, Tbuf, b5, w6d, b6dp, out);
}

// Round 7
// 333.145 us; speedup vs baseline: 1.1911x; 1.1911x over previous
//
#include <hip/hip_runtime.h>
#include <hip/hip_bf16.h>

// ---------------------------------------------------------------------------
// ramsey_NN: node MLP (3 layers, train-mode BN) + all-pairs edge head.
// N=2048, F=64, H=128, C=2.  E = N(N-1)/2 = 2096128.
//
// R7 vs R6 (R6 regressed: packed-stat accumulators blew edge_p1 to VGPR=160,
// 3 waves/SIMD, 142 us; these kernels scale ~linearly with resident waves):
//   * edge_p1: minimal live-set — inline lrelu, S2/Q2 accumulators only
//     (8 regs). Zero barriers, per-XCD SQe8 atomics kept.
//   * edge_p2: no dpAll; per-i acc[4] (dead after each i), 2-shfl +
//     single-writer PLAIN store to sV[w][i][.], cross-wave sum tail (R6's,
//     which passed). No LDS atomics.
//   * k_bi XCD-aligned: 256 blocks x 8 nodes so T[row-group g] is produced
//     on XCD g&7 == the XCD that consumes it (decode_tile pins row g there).
// ---------------------------------------------------------------------------

typedef short short8 __attribute__((ext_vector_type(8)));   // 8 x bf16
typedef float floatx4 __attribute__((ext_vector_type(4)));  // MFMA C/D
typedef float float2v __attribute__((ext_vector_type(2)));  // packed f32 pair

#define NN 2048
#define EPSV 1e-5f
#define EDGEF 2096128.f

__device__ __forceinline__ float bf2f(short s) {
    return __uint_as_float(((unsigned)(unsigned short)s) << 16);
}
__device__ __forceinline__ short f2bf(float f) {   // RNE
    unsigned u = __float_as_uint(f);
    unsigned r = (u + 0x7FFFu + ((u >> 16) & 1u)) >> 16;
    return (short)r;
}
__device__ __forceinline__ float lrelu(float x) { return fmaxf(x, 0.01f * x); }
__device__ __forceinline__ float2v lrelu2(float2v z) {
    float2v r; r.x = fmaxf(z.x, 0.01f * z.x); r.y = fmaxf(z.y, 0.01f * z.y);
    return r;
}
__device__ __forceinline__ float2v fma2(float2v a, float2v b, float2v c) {
    float2v r; r.x = fmaf(a.x, b.x, c.x); r.y = fmaf(a.y, b.y, c.y); return r;
}

// fragment-physical chunk index (16x16x32 bf16, A/B identity layout)
__device__ __forceinline__ int physB(int h, int f) {
    return ((((h >> 4) * 2 + (f >> 5)) * 64 + ((f >> 3) & 3) * 16 + (h & 15)) * 8) + (f & 7);
}

// 1-D active-tile decode: rows-of-8 nodes, j-tiles of 64.
// Row ig8 pinned to XCD ig8%8 (blockIdx%8 round-robin heuristic).
// Per-XCD slots: sum_{m=0}^{31}(32-m)=528; grid = 4224.
__device__ __forceinline__ void decode_tile(int bid, int& i0, int& j0, bool& str) {
    int s = bid >> 3, m = 0;
#pragma unroll 1
    while (s >= 32 - m) { s -= 32 - m; ++m; }
    i0 = ((bid & 7) + (m << 3)) * 8;
    j0 = (m + s) * 64;
    str = (s == 0);
}

// ---------------- node layer 1 (+ W5->bf16 conversion on blocks 0..31) -------
__global__ __launch_bounds__(256) void k_l1(const float* __restrict__ nf,
                                            const float* __restrict__ W1,
                                            const float* __restrict__ b1,
                                            const float* __restrict__ W5,
                                            float* __restrict__ act1,
                                            float* __restrict__ stat1,
                                            short* __restrict__ w5bf) {
    __shared__ float xl[8 * 64];
    __shared__ float sS[128], sQ[128];
    int t = threadIdx.x, n0 = blockIdx.x * 8;
    if (blockIdx.x < 32) {                     // fused W5 -> bf16 frag-physical
        int idx = blockIdx.x * 256 + t;        // f*128+h over 8192
        w5bf[physB(idx & 127, idx >> 7)] = f2bf(W5[idx]);
    }
    if (t < 128) { sS[t] = 0.f; sQ[t] = 0.f; }
    xl[t] = nf[(size_t)n0 * 64 + t];
    xl[t + 256] = nf[(size_t)n0 * 64 + t + 256];
    __syncthreads();
    int nl = t >> 5, h0 = (t & 31) * 4;
    float acc[4];
    for (int k = 0; k < 4; ++k) acc[k] = b1[h0 + k];
    for (int f = 0; f < 64; ++f) {
        float r = xl[nl * 64 + f];
        const float* wr = W1 + f * 128 + h0;
        for (int k = 0; k < 4; ++k) acc[k] = fmaf(r, wr[k], acc[k]);
    }
    for (int k = 0; k < 4; ++k) {
        float a = lrelu(acc[k]);
        act1[(size_t)(n0 + nl) * 128 + h0 + k] = a;
        atomicAdd(&sS[h0 + k], a);
        atomicAdd(&sQ[h0 + k], a * a);
    }
    __syncthreads();
    if (t < 128) atomicAdd(&stat1[t], sS[t]);
    else atomicAdd(&stat1[t], sQ[t - 128]);
}

// ---------------- node layer 2 ----------------------------------------------
__global__ __launch_bounds__(256) void k_l2(const float* __restrict__ act1,
                                            const float* __restrict__ stat1,
                                            const float* __restrict__ g1,
                                            const float* __restrict__ be1,
                                            const float* __restrict__ W2,
                                            const float* __restrict__ b2,
                                            float* __restrict__ act2,
                                            float* __restrict__ stat2) {
    __shared__ float a1n[8 * 128];
    __shared__ float sS[128], sQ[128];
    int t = threadIdx.x, n0 = blockIdx.x * 8;
    if (t < 128) { sS[t] = 0.f; sQ[t] = 0.f; }
    for (int k = 0; k < 4; ++k) {
        int e = t + 256 * k;
        int nl = e >> 7, h = e & 127;
        float m = stat1[h] * (1.f / 2048.f);
        float v = stat1[128 + h] * (1.f / 2048.f) - m * m;
        float sc = rsqrtf(v + EPSV);
        a1n[e] = (act1[(size_t)(n0 + nl) * 128 + h] - m) * sc * g1[h] + be1[h];
    }
    __syncthreads();
    int nl = t >> 5, h0 = (t & 31) * 4;
    float acc[4];
    for (int k = 0; k < 4; ++k) acc[k] = b2[h0 + k];
    for (int hi = 0; hi < 128; ++hi) {
        float r = a1n[nl * 128 + hi];
        const float* wr = W2 + hi * 128 + h0;
        for (int k = 0; k < 4; ++k) acc[k] = fmaf(r, wr[k], acc[k]);
    }
    for (int k = 0; k < 4; ++k) {
        float a = lrelu(acc[k]);
        act2[(size_t)(n0 + nl) * 128 + h0 + k] = a;
        atomicAdd(&sS[h0 + k], a);
        atomicAdd(&sQ[h0 + k], a * a);
    }
    __syncthreads();
    if (t < 128) atomicAdd(&stat2[t], sS[t]);
    else atomicAdd(&stat2[t], sQ[t - 128]);
}

// ---------------- node layer 3 + residual -> hb (bf16) -----------------------
__global__ __launch_bounds__(256) void k_l3(const float* __restrict__ act2,
                                            const float* __restrict__ stat2,
                                            const float* __restrict__ g2,
                                            const float* __restrict__ be2,
                                            const float* __restrict__ W3,
                                            const float* __restrict__ b3,
                                            const float* __restrict__ nf,
                                            short* __restrict__ hb) {
    __shared__ float a2n[8 * 128];
    int t = threadIdx.x, n0 = blockIdx.x * 8;
    for (int k = 0; k < 4; ++k) {
        int e = t + 256 * k;
        int nl = e >> 7, h = e & 127;
        float m = stat2[h] * (1.f / 2048.f);
        float v = stat2[128 + h] * (1.f / 2048.f) - m * m;
        float sc = rsqrtf(v + EPSV);
        a2n[e] = (act2[(size_t)(n0 + nl) * 128 + h] - m) * sc * g2[h] + be2[h];
    }
    __syncthreads();
    int nl = t >> 5, f0 = (t & 31) * 2;
    float acc[2] = {0.f, 0.f};
    for (int hi = 0; hi < 128; ++hi) {
        float r = a2n[nl * 128 + hi];
        const float* wr = W3 + hi * 64 + f0;
        acc[0] = fmaf(r, wr[0], acc[0]);
        acc[1] = fmaf(r, wr[1], acc[1]);
    }
    float v0 = acc[0] + b3[f0] + nf[(size_t)(n0 + nl) * 64 + f0];
    float v1 = acc[1] + b3[f0 + 1] + nf[(size_t)(n0 + nl) * 64 + f0 + 1];
    unsigned p = (unsigned)(unsigned short)f2bf(v0) |
                 ((unsigned)(unsigned short)f2bf(v1) << 16);
    ((unsigned*)hb)[(size_t)(n0 + nl) * 32 + (f0 >> 1)] = p;
}

// ---------------- T = diag(h_i) @ W5, XCD-aligned (256 blocks x 8 nodes) -----
// Block b handles nodes 8b..8b+7 (row-group b); dispatch heuristic puts block
// b on XCD b%8 == the XCD decode_tile assigns row-group b to.
__global__ __launch_bounds__(256) void k_bi(const short* __restrict__ w5bf,
                                            const short* __restrict__ hb,
                                            short* __restrict__ T) {
    int b = blockIdx.x, t = threadIdx.x;
    __shared__ short sHi[8 * 64];
    if (t < 64) ((short8*)sHi)[t] = ((const short8*)(hb + (size_t)b * 512))[t];
    __syncthreads();
    for (int i = 0; i < 8; ++i) {
        short8* dst = (short8*)(T + (size_t)(b * 8 + i) * 8192);
#pragma unroll
        for (int k = 0; k < 4; ++k) {
            int c = t + 256 * k;                 // chunk 0..1023
            int ks = (c >> 6) & 1, quad = (c & 63) >> 4;
            int fb = ks * 32 + quad * 8;
            short8 wv = ((const short8*)w5bf)[c];
            short8 hv = *(const short8*)(sHi + i * 64 + fb);
            short8 ov;
#pragma unroll
            for (int e = 0; e < 8; ++e) ov[e] = f2bf(bf2f(wv[e]) * bf2f(hv[e]));
            dst[c] = ov;
        }
    }
}

// ---------------- BN+softmax fold (1 block) ----------------------------------
__global__ void k_mid(const float* __restrict__ SQe8, const float* __restrict__ W6,
                      const float* __restrict__ b6, const float* __restrict__ g5,
                      const float* __restrict__ be5, float* __restrict__ w6d,
                      float* __restrict__ b6d) {
    __shared__ float part[128];
    int h = threadIdx.x;
    float s = 0.f, q = 0.f;
    for (int x = 0; x < 8; ++x) {
        s += SQe8[x * 256 + h];
        q += SQe8[x * 256 + 128 + h];
    }
    float m = s / EDGEF;
    float v = q / EDGEF - m * m;
    float sc = rsqrtf(v + EPSV);
    float dW = W6[h * 2] - W6[h * 2 + 1];
    float sg = sc * g5[h];
    w6d[h] = sg * dW;
    part[h] = (be5[h] - m * sg) * dW;
    __syncthreads();
    if (h == 0) {
        float acc = b6[0] - b6[1];
        for (int k = 0; k < 128; ++k) acc += part[k];
        b6d[0] = acc;
    }
}

// ---------------- edge pass 1: BN stats (zero barriers, min live-set) --------
__global__ __launch_bounds__(256) void edge_p1(
    const short* __restrict__ hb, const short* __restrict__ T,
    const float* __restrict__ b5, float* __restrict__ SQe8)
{
    int i0, j0; bool str;
    decode_tile(blockIdx.x, i0, j0, str);

    int t = threadIdx.x, lane = t & 63, w = t >> 6;
    int quad = lane >> 4, col = lane & 15;

    short8 hfr[4][2];
#pragma unroll
    for (int mt = 0; mt < 4; ++mt)
#pragma unroll
        for (int ks = 0; ks < 2; ++ks)
            hfr[mt][ks] = *(const short8*)(hb + (size_t)(j0 + mt * 16 + col) * 64 + ks * 32 + quad * 8);

    const short* Tb = T + (size_t)i0 * 8192;
    int toff[2][2];
#pragma unroll
    for (int n = 0; n < 2; ++n)
#pragma unroll
        for (int ks = 0; ks < 2; ++ks)
            toff[n][ks] = ((((w * 2 + n) * 2 + ks) * 64) + lane) * 8;

    float b5c[2] = { b5[w * 32 + col], b5[w * 32 + 16 + col] };
    float2v S2[2], Q2[2];
#pragma unroll
    for (int n = 0; n < 2; ++n) { S2[n] = 0.f; Q2[n] = 0.f; }

    short8 ta[2][2], tb[2][2];
#pragma unroll
    for (int n = 0; n < 2; ++n)
#pragma unroll
        for (int ks = 0; ks < 2; ++ks)
            ta[n][ks] = *(const short8*)(Tb + toff[n][ks]);

    auto body1 = [&](int i, short8 (&tc)[2][2]) {
        int igi = i0 + i;
#pragma unroll
        for (int n = 0; n < 2; ++n) {
#pragma unroll
            for (int mt = 0; mt < 4; ++mt) {
                floatx4 c = {b5c[n], b5c[n], b5c[n], b5c[n]};
                c = __builtin_amdgcn_mfma_f32_16x16x32_bf16(hfr[mt][0], tc[n][0], c, 0, 0, 0);
                c = __builtin_amdgcn_mfma_f32_16x16x32_bf16(hfr[mt][1], tc[n][1], c, 0, 0, 0);
                float2v z01, z23;
                if (!str) {
                    z01.x = c[0]; z01.y = c[1];
                    z23.x = c[2]; z23.y = c[3];
                } else {
                    int jb = j0 + mt * 16 + quad * 4;
                    z01.x = (jb + 0 > igi) ? c[0] : 0.f;
                    z01.y = (jb + 1 > igi) ? c[1] : 0.f;
                    z23.x = (jb + 2 > igi) ? c[2] : 0.f;
                    z23.y = (jb + 3 > igi) ? c[3] : 0.f;
                }
                float2v a01 = lrelu2(z01), a23 = lrelu2(z23);
                S2[n] += a01 + a23;
                Q2[n] = fma2(a01, a01, Q2[n]);
                Q2[n] = fma2(a23, a23, Q2[n]);
            }
        }
    };

    for (int ii = 0; ii < 8; ii += 2) {
        {
            const short* Tn = Tb + (size_t)(ii + 1) * 8192;
#pragma unroll
            for (int n = 0; n < 2; ++n)
#pragma unroll
                for (int ks = 0; ks < 2; ++ks)
                    tb[n][ks] = *(const short8*)(Tn + toff[n][ks]);
        }
        body1(ii, ta);
        if (ii + 2 < 8) {
            const short* Tn = Tb + (size_t)(ii + 2) * 8192;
#pragma unroll
            for (int n = 0; n < 2; ++n)
#pragma unroll
                for (int ks = 0; ks < 2; ++ks)
                    ta[n][ks] = *(const short8*)(Tn + toff[n][ks]);
        }
        body1(ii + 1, tb);
    }

    float* dst = SQe8 + (blockIdx.x & 7) * 256;
#pragma unroll
    for (int n = 0; n < 2; ++n) {
        float Sa = S2[n].x + S2[n].y;
        float Qa = Q2[n].x + Q2[n].y;
        Sa += __shfl_xor(Sa, 16); Sa += __shfl_xor(Sa, 32);
        Qa += __shfl_xor(Qa, 16); Qa += __shfl_xor(Qa, 32);
        if (quad == 0) {
            atomicAdd(&dst[w * 32 + n * 16 + col], Sa);
            atomicAdd(&dst[128 + w * 32 + n * 16 + col], Qa);
        }
    }
}

// ---------------- edge pass 2: probabilities + symmetric write ---------------
__global__ __launch_bounds__(256) void edge_p2(
    const short* __restrict__ hb, const short* __restrict__ T,
    const float* __restrict__ b5, const float* __restrict__ w6d,
    const float* __restrict__ b6dp, float* __restrict__ out)
{
    int i0, j0; bool str;
    decode_tile(blockIdx.x, i0, j0, str);
    __shared__ float sV[4][8][64];    // per-wave partial h-sums (8 KB)
    __shared__ float sP[8][65];       // probs, padded (mirror transpose)

    int t = threadIdx.x, lane = t & 63, w = t >> 6;
    int quad = lane >> 4, col = lane & 15;

    float bb = b6dp[0];
    float b5q[2][4];
    float2v wq[2][2];                 // w6d at (m, r01/r23)
#pragma unroll
    for (int m = 0; m < 2; ++m)
#pragma unroll
        for (int r = 0; r < 4; ++r) {
            int h = w * 32 + m * 16 + quad * 4 + r;
            b5q[m][r] = b5[h];
            ((float*)&wq[m][r >> 1])[r & 1] = w6d[h];
        }

    short8 hfr[4][2];
#pragma unroll
    for (int mt = 0; mt < 4; ++mt)
#pragma unroll
        for (int ks = 0; ks < 2; ++ks)
            hfr[mt][ks] = *(const short8*)(hb + (size_t)(j0 + mt * 16 + col) * 64 + ks * 32 + quad * 8);

    const short* Tb = T + (size_t)i0 * 8192;
    int toff[2][2];
#pragma unroll
    for (int m = 0; m < 2; ++m)
#pragma unroll
        for (int ks = 0; ks < 2; ++ks)
            toff[m][ks] = ((((w * 2 + m) * 2 + ks) * 64) + lane) * 8;

    short8 ta[2][2], tb[2][2];
#pragma unroll
    for (int m = 0; m < 2; ++m)
#pragma unroll
        for (int ks = 0; ks < 2; ++ks)
            ta[m][ks] = *(const short8*)(Tb + toff[m][ks]);

    auto body2 = [&](int i, short8 (&tc)[2][2]) {
        float2v acc[4];
#pragma unroll
        for (int k = 0; k < 4; ++k) acc[k] = 0.f;
#pragma unroll
        for (int m = 0; m < 2; ++m) {
#pragma unroll
            for (int nj = 0; nj < 4; ++nj) {
                floatx4 c = {b5q[m][0], b5q[m][1], b5q[m][2], b5q[m][3]};
                c = __builtin_amdgcn_mfma_f32_16x16x32_bf16(tc[m][0], hfr[nj][0], c, 0, 0, 0);
                c = __builtin_amdgcn_mfma_f32_16x16x32_bf16(tc[m][1], hfr[nj][1], c, 0, 0, 0);
                float2v z01, z23;
                z01.x = c[0]; z01.y = c[1];
                z23.x = c[2]; z23.y = c[3];
                acc[nj] = fma2(lrelu2(z01), wq[m][0], acc[nj]);
                acc[nj] = fma2(lrelu2(z23), wq[m][1], acc[nj]);
            }
        }
        // per-i tail: quad-butterfly + single-writer plain store (no atomics)
#pragma unroll
        for (int nj = 0; nj < 4; ++nj) {
            float v = acc[nj].x + acc[nj].y;
            v += __shfl_xor(v, 16);
            v += __shfl_xor(v, 32);
            if (quad == 0) sV[w][i][nj * 16 + col] = v;
        }
    };

    for (int ii = 0; ii < 8; ii += 2) {
        {
            const short* Tn = Tb + (size_t)(ii + 1) * 8192;
#pragma unroll
            for (int m = 0; m < 2; ++m)
#pragma unroll
                for (int ks = 0; ks < 2; ++ks)
                    tb[m][ks] = *(const short8*)(Tn + toff[m][ks]);
        }
        body2(ii, ta);
        if (ii + 2 < 8) {
            const short* Tn = Tb + (size_t)(ii + 2) * 8192;
#pragma unroll
            for (int m = 0; m < 2; ++m)
#pragma unroll
                for (int ks = 0; ks < 2; ++ks)
                    ta[m][ks] = *(const short8*)(Tn + toff[m][ks]);
        }
        body2(ii + 1, tb);
    }
    __syncthreads();

    // cross-wave sum + sigmoid + direct write (coalesced)
#pragma unroll
    for (int k = 0; k < 2; ++k) {
        int e = t + 256 * k;          // 0..511
        int il = e >> 6, jl = e & 63;
        float v = bb + sV[0][il][jl] + sV[1][il][jl] + sV[2][il][jl] + sV[3][il][jl];
        float p = 1.f / (1.f + __expf(-v));
        sP[il][jl] = p;
        int ig = i0 + il, jg = j0 + jl;
        float2v pr;
        if (!str || jg > ig) {
            pr.x = p; pr.y = 1.f - p;
            *(float2v*)(out + ((size_t)ig * NN + jg) * 2) = pr;
        } else if (jg == ig) {
            pr.x = 0.f; pr.y = 0.f;
            *(float2v*)(out + ((size_t)ig * NN + jg) * 2) = pr;
        }
    }
    __syncthreads();

    if (!str) {
        // mirror: 64 rows x 16 floats, float4 per thread
        int jr = t >> 2, f1 = (t & 3) * 4;
        float4 u;
#pragma unroll
        for (int e = 0; e < 4; ++e) {
            int ff = f1 + e;
            float p = sP[ff >> 1][jr];
            ((float*)&u)[e] = (ff & 1) ? 1.f - p : p;
        }
        *(float4*)(out + ((size_t)(j0 + jr) * NN + i0) * 2 + f1) = u;
    } else {
#pragma unroll
        for (int e = 0; e < 4; ++e) {     // mirror 64x8x2 = 1024 floats
            int f = t * 4 + e;
            int jr = f >> 4, ff = f & 15;
            int il = ff >> 1, c2 = ff & 1;
            int jg = j0 + jr, ig = i0 + il;
            if (jg > ig) {
                float p = sP[il][jr];
                out[((size_t)jg * NN + ig) * 2 + c2] = c2 ? 1.f - p : p;
            }
        }
    }
}

// ---------------------------------------------------------------------------
extern "C" void kernel_launch(void* const* d_in, const int* in_sizes, int n_in,
                              void* d_out, int out_size, void* d_ws, size_t ws_size,
                              hipStream_t stream) {
    const float* nf  = (const float*)d_in[1];   // d_in[0]=x unused (ref ignores it)
    const float* W1  = (const float*)d_in[2];
    const float* b1  = (const float*)d_in[3];
    const float* g1  = (const float*)d_in[4];
    const float* be1 = (const float*)d_in[5];
    const float* W2  = (const float*)d_in[6];
    const float* b2  = (const float*)d_in[7];
    const float* g2  = (const float*)d_in[8];
    const float* be2 = (const float*)d_in[9];
    const float* W3  = (const float*)d_in[10];
    const float* b3  = (const float*)d_in[11];
    const float* W5  = (const float*)d_in[12];
    const float* b5  = (const float*)d_in[13];
    const float* g5  = (const float*)d_in[14];
    const float* be5 = (const float*)d_in[15];
    const float* W6  = (const float*)d_in[16];
    const float* b6  = (const float*)d_in[17];
    float* out = (float*)d_out;

    float* wsf   = (float*)d_ws;
    float* stat1 = wsf;                 // 256
    float* stat2 = wsf + 256;           // 256
    float* SQe8  = wsf + 512;           // 8*256 = 2048 (per-XCD stat copies)
    float* w6d   = wsf + 2560;          // 128
    float* b6dp  = wsf + 2688;          // 1 (pad to 4096)
    float* act1  = wsf + 4096;          // 262144
    float* act2  = act1 + 262144;       // 262144
    short* hb    = (short*)(act2 + 262144);   // 131072 bf16
    short* w5bf  = hb + 131072;               // 8192 bf16
    short* Tbuf  = w5bf + 8192;               // 2048*8192 bf16 = 32 MB

    hipMemsetAsync(d_ws, 0, 4096 * sizeof(float), stream);

    k_l1<<<256, 256, 0, stream>>>(nf, W1, b1, W5, act1, stat1, w5bf);
    k_l2<<<256, 256, 0, stream>>>(act1, stat1, g1, be1, W2, b2, act2, stat2);
    k_l3<<<256, 256, 0, stream>>>(act2, stat2, g2, be2, W3, b3, nf, hb);
    k_bi<<<256, 256, 0, stream>>>(w5bf, hb, Tbuf);

    edge_p1<<<4224, 256, 0, stream>>>(hb, Tbuf, b5, SQe8);
    k_mid<<<1, 128, 0, stream>>>(SQe8, W6, b6, g5, be5, w6d, b6dp);
    edge_p2<<<4224, 256, 0, stream>>>(hb, Tbuf, b5, w6d, b6dp, out);
}

// Round 8
// 255.853 us; speedup vs baseline: 1.5509x; 1.3021x over previous
//
#include <hip/hip_runtime.h>
#include <hip/hip_bf16.h>

// ---------------------------------------------------------------------------
// ramsey_NN: node MLP (3 layers, train-mode BN) + all-pairs edge head.
// N=2048, F=64, H=128, C=2.  E = N(N-1)/2 = 2096128.
//
// R8 vs R7 (R7 analysis: true residency ~1 block/CU — unified VGPR+AGPR file
// exceeded 256 regs; plus ~1030 VALU-cyc per i-iter from if-converted
// straddle masking in every block):
//   * edge_p1/p2: __launch_bounds__(256, 4) — cap total regs at 128,
//     4 waves/SIMD.
//   * edge_p1: str branch hoisted OUT of the i-loop (clean + masked loop
//     copies; only 64/4224 blocks take the masked path).
//   * everything else unchanged from R7 (which passed).
// ---------------------------------------------------------------------------

typedef short short8 __attribute__((ext_vector_type(8)));   // 8 x bf16
typedef float floatx4 __attribute__((ext_vector_type(4)));  // MFMA C/D
typedef float float2v __attribute__((ext_vector_type(2)));  // packed f32 pair

#define NN 2048
#define EPSV 1e-5f
#define EDGEF 2096128.f

__device__ __forceinline__ float bf2f(short s) {
    return __uint_as_float(((unsigned)(unsigned short)s) << 16);
}
__device__ __forceinline__ short f2bf(float f) {   // RNE
    unsigned u = __float_as_uint(f);
    unsigned r = (u + 0x7FFFu + ((u >> 16) & 1u)) >> 16;
    return (short)r;
}
__device__ __forceinline__ float lrelu(float x) { return fmaxf(x, 0.01f * x); }
__device__ __forceinline__ float2v lrelu2(float2v z) {
    float2v r; r.x = fmaxf(z.x, 0.01f * z.x); r.y = fmaxf(z.y, 0.01f * z.y);
    return r;
}
__device__ __forceinline__ float2v fma2(float2v a, float2v b, float2v c) {
    float2v r; r.x = fmaf(a.x, b.x, c.x); r.y = fmaf(a.y, b.y, c.y); return r;
}

// fragment-physical chunk index (16x16x32 bf16, A/B identity layout)
__device__ __forceinline__ int physB(int h, int f) {
    return ((((h >> 4) * 2 + (f >> 5)) * 64 + ((f >> 3) & 3) * 16 + (h & 15)) * 8) + (f & 7);
}

// 1-D active-tile decode: rows-of-8 nodes, j-tiles of 64.
// Row ig8 pinned to XCD ig8%8 (blockIdx%8 round-robin heuristic).
// Per-XCD slots: sum_{m=0}^{31}(32-m)=528; grid = 4224.
__device__ __forceinline__ void decode_tile(int bid, int& i0, int& j0, bool& str) {
    int s = bid >> 3, m = 0;
#pragma unroll 1
    while (s >= 32 - m) { s -= 32 - m; ++m; }
    i0 = ((bid & 7) + (m << 3)) * 8;
    j0 = (m + s) * 64;
    str = (s == 0);
}

// ---------------- node layer 1 (+ W5->bf16 conversion on blocks 0..31) -------
__global__ __launch_bounds__(256) void k_l1(const float* __restrict__ nf,
                                            const float* __restrict__ W1,
                                            const float* __restrict__ b1,
                                            const float* __restrict__ W5,
                                            float* __restrict__ act1,
                                            float* __restrict__ stat1,
                                            short* __restrict__ w5bf) {
    __shared__ float xl[8 * 64];
    __shared__ float sS[128], sQ[128];
    int t = threadIdx.x, n0 = blockIdx.x * 8;
    if (blockIdx.x < 32) {                     // fused W5 -> bf16 frag-physical
        int idx = blockIdx.x * 256 + t;        // f*128+h over 8192
        w5bf[physB(idx & 127, idx >> 7)] = f2bf(W5[idx]);
    }
    if (t < 128) { sS[t] = 0.f; sQ[t] = 0.f; }
    xl[t] = nf[(size_t)n0 * 64 + t];
    xl[t + 256] = nf[(size_t)n0 * 64 + t + 256];
    __syncthreads();
    int nl = t >> 5, h0 = (t & 31) * 4;
    float acc[4];
    for (int k = 0; k < 4; ++k) acc[k] = b1[h0 + k];
    for (int f = 0; f < 64; ++f) {
        float r = xl[nl * 64 + f];
        const float* wr = W1 + f * 128 + h0;
        for (int k = 0; k < 4; ++k) acc[k] = fmaf(r, wr[k], acc[k]);
    }
    for (int k = 0; k < 4; ++k) {
        float a = lrelu(acc[k]);
        act1[(size_t)(n0 + nl) * 128 + h0 + k] = a;
        atomicAdd(&sS[h0 + k], a);
        atomicAdd(&sQ[h0 + k], a * a);
    }
    __syncthreads();
    if (t < 128) atomicAdd(&stat1[t], sS[t]);
    else atomicAdd(&stat1[t], sQ[t - 128]);
}

// ---------------- node layer 2 ----------------------------------------------
__global__ __launch_bounds__(256) void k_l2(const float* __restrict__ act1,
                                            const float* __restrict__ stat1,
                                            const float* __restrict__ g1,
                                            const float* __restrict__ be1,
                                            const float* __restrict__ W2,
                                            const float* __restrict__ b2,
                                            float* __restrict__ act2,
                                            float* __restrict__ stat2) {
    __shared__ float a1n[8 * 128];
    __shared__ float sS[128], sQ[128];
    int t = threadIdx.x, n0 = blockIdx.x * 8;
    if (t < 128) { sS[t] = 0.f; sQ[t] = 0.f; }
    for (int k = 0; k < 4; ++k) {
        int e = t + 256 * k;
        int nl = e >> 7, h = e & 127;
        float m = stat1[h] * (1.f / 2048.f);
        float v = stat1[128 + h] * (1.f / 2048.f) - m * m;
        float sc = rsqrtf(v + EPSV);
        a1n[e] = (act1[(size_t)(n0 + nl) * 128 + h] - m) * sc * g1[h] + be1[h];
    }
    __syncthreads();
    int nl = t >> 5, h0 = (t & 31) * 4;
    float acc[4];
    for (int k = 0; k < 4; ++k) acc[k] = b2[h0 + k];
    for (int hi = 0; hi < 128; ++hi) {
        float r = a1n[nl * 128 + hi];
        const float* wr = W2 + hi * 128 + h0;
        for (int k = 0; k < 4; ++k) acc[k] = fmaf(r, wr[k], acc[k]);
    }
    for (int k = 0; k < 4; ++k) {
        float a = lrelu(acc[k]);
        act2[(size_t)(n0 + nl) * 128 + h0 + k] = a;
        atomicAdd(&sS[h0 + k], a);
        atomicAdd(&sQ[h0 + k], a * a);
    }
    __syncthreads();
    if (t < 128) atomicAdd(&stat2[t], sS[t]);
    else atomicAdd(&stat2[t], sQ[t - 128]);
}

// ---------------- node layer 3 + residual -> hb (bf16) -----------------------
__global__ __launch_bounds__(256) void k_l3(const float* __restrict__ act2,
                                            const float* __restrict__ stat2,
                                            const float* __restrict__ g2,
                                            const float* __restrict__ be2,
                                            const float* __restrict__ W3,
                                            const float* __restrict__ b3,
                                            const float* __restrict__ nf,
                                            short* __restrict__ hb) {
    __shared__ float a2n[8 * 128];
    int t = threadIdx.x, n0 = blockIdx.x * 8;
    for (int k = 0; k < 4; ++k) {
        int e = t + 256 * k;
        int nl = e >> 7, h = e & 127;
        float m = stat2[h] * (1.f / 2048.f);
        float v = stat2[128 + h] * (1.f / 2048.f) - m * m;
        float sc = rsqrtf(v + EPSV);
        a2n[e] = (act2[(size_t)(n0 + nl) * 128 + h] - m) * sc * g2[h] + be2[h];
    }
    __syncthreads();
    int nl = t >> 5, f0 = (t & 31) * 2;
    float acc[2] = {0.f, 0.f};
    for (int hi = 0; hi < 128; ++hi) {
        float r = a2n[nl * 128 + hi];
        const float* wr = W3 + hi * 64 + f0;
        acc[0] = fmaf(r, wr[0], acc[0]);
        acc[1] = fmaf(r, wr[1], acc[1]);
    }
    float v0 = acc[0] + b3[f0] + nf[(size_t)(n0 + nl) * 64 + f0];
    float v1 = acc[1] + b3[f0 + 1] + nf[(size_t)(n0 + nl) * 64 + f0 + 1];
    unsigned p = (unsigned)(unsigned short)f2bf(v0) |
                 ((unsigned)(unsigned short)f2bf(v1) << 16);
    ((unsigned*)hb)[(size_t)(n0 + nl) * 32 + (f0 >> 1)] = p;
}

// ---------------- T = diag(h_i) @ W5, XCD-aligned (256 blocks x 8 nodes) -----
__global__ __launch_bounds__(256) void k_bi(const short* __restrict__ w5bf,
                                            const short* __restrict__ hb,
                                            short* __restrict__ T) {
    int b = blockIdx.x, t = threadIdx.x;
    __shared__ short sHi[8 * 64];
    if (t < 64) ((short8*)sHi)[t] = ((const short8*)(hb + (size_t)b * 512))[t];
    __syncthreads();
    for (int i = 0; i < 8; ++i) {
        short8* dst = (short8*)(T + (size_t)(b * 8 + i) * 8192);
#pragma unroll
        for (int k = 0; k < 4; ++k) {
            int c = t + 256 * k;                 // chunk 0..1023
            int ks = (c >> 6) & 1, quad = (c & 63) >> 4;
            int fb = ks * 32 + quad * 8;
            short8 wv = ((const short8*)w5bf)[c];
            short8 hv = *(const short8*)(sHi + i * 64 + fb);
            short8 ov;
#pragma unroll
            for (int e = 0; e < 8; ++e) ov[e] = f2bf(bf2f(wv[e]) * bf2f(hv[e]));
            dst[c] = ov;
        }
    }
}

// ---------------- BN+softmax fold (1 block) ----------------------------------
__global__ void k_mid(const float* __restrict__ SQe8, const float* __restrict__ W6,
                      const float* __restrict__ b6, const float* __restrict__ g5,
                      const float* __restrict__ be5, float* __restrict__ w6d,
                      float* __restrict__ b6d) {
    __shared__ float part[128];
    int h = threadIdx.x;
    float s = 0.f, q = 0.f;
    for (int x = 0; x < 8; ++x) {
        s += SQe8[x * 256 + h];
        q += SQe8[x * 256 + 128 + h];
    }
    float m = s / EDGEF;
    float v = q / EDGEF - m * m;
    float sc = rsqrtf(v + EPSV);
    float dW = W6[h * 2] - W6[h * 2 + 1];
    float sg = sc * g5[h];
    w6d[h] = sg * dW;
    part[h] = (be5[h] - m * sg) * dW;
    __syncthreads();
    if (h == 0) {
        float acc = b6[0] - b6[1];
        for (int k = 0; k < 128; ++k) acc += part[k];
        b6d[0] = acc;
    }
}

// ---------------- edge pass 1: BN stats --------------------------------------
// __launch_bounds__(256,4): cap total regs (unified VGPR+AGPR) at 128 ->
// 4 waves/SIMD. str branch hoisted out of the i-loop.
__global__ __launch_bounds__(256, 4) void edge_p1(
    const short* __restrict__ hb, const short* __restrict__ T,
    const float* __restrict__ b5, float* __restrict__ SQe8)
{
    int i0, j0; bool str;
    decode_tile(blockIdx.x, i0, j0, str);

    int t = threadIdx.x, lane = t & 63, w = t >> 6;
    int quad = lane >> 4, col = lane & 15;

    short8 hfr[4][2];
#pragma unroll
    for (int mt = 0; mt < 4; ++mt)
#pragma unroll
        for (int ks = 0; ks < 2; ++ks)
            hfr[mt][ks] = *(const short8*)(hb + (size_t)(j0 + mt * 16 + col) * 64 + ks * 32 + quad * 8);

    const short* Tb = T + (size_t)i0 * 8192;
    int toff[2][2];
#pragma unroll
    for (int n = 0; n < 2; ++n)
#pragma unroll
        for (int ks = 0; ks < 2; ++ks)
            toff[n][ks] = ((((w * 2 + n) * 2 + ks) * 64) + lane) * 8;

    float b5c[2] = { b5[w * 32 + col], b5[w * 32 + 16 + col] };
    float2v S2[2], Q2[2];
#pragma unroll
    for (int n = 0; n < 2; ++n) { S2[n] = 0.f; Q2[n] = 0.f; }

    short8 ta[2][2], tb[2][2];

    auto prefetch = [&](short8 (&dst)[2][2], int i) {
        const short* Tn = Tb + (size_t)i * 8192;
#pragma unroll
        for (int n = 0; n < 2; ++n)
#pragma unroll
            for (int ks = 0; ks < 2; ++ks)
                dst[n][ks] = *(const short8*)(Tn + toff[n][ks]);
    };

    // clean body: no triangle masking (4160 of 4224 blocks)
    auto bodyC = [&](short8 (&tc)[2][2]) {
#pragma unroll
        for (int n = 0; n < 2; ++n) {
#pragma unroll
            for (int mt = 0; mt < 4; ++mt) {
                floatx4 c = {b5c[n], b5c[n], b5c[n], b5c[n]};
                c = __builtin_amdgcn_mfma_f32_16x16x32_bf16(hfr[mt][0], tc[n][0], c, 0, 0, 0);
                c = __builtin_amdgcn_mfma_f32_16x16x32_bf16(hfr[mt][1], tc[n][1], c, 0, 0, 0);
                float2v z01, z23;
                z01.x = c[0]; z01.y = c[1];
                z23.x = c[2]; z23.y = c[3];
                float2v a01 = lrelu2(z01), a23 = lrelu2(z23);
                S2[n] += a01 + a23;
                Q2[n] = fma2(a01, a01, Q2[n]);
                Q2[n] = fma2(a23, a23, Q2[n]);
            }
        }
    };

    // masked body: diagonal-straddling blocks only (64 of 4224)
    auto bodyM = [&](int i, short8 (&tc)[2][2]) {
        int igi = i0 + i;
#pragma unroll
        for (int n = 0; n < 2; ++n) {
#pragma unroll
            for (int mt = 0; mt < 4; ++mt) {
                floatx4 c = {b5c[n], b5c[n], b5c[n], b5c[n]};
                c = __builtin_amdgcn_mfma_f32_16x16x32_bf16(hfr[mt][0], tc[n][0], c, 0, 0, 0);
                c = __builtin_amdgcn_mfma_f32_16x16x32_bf16(hfr[mt][1], tc[n][1], c, 0, 0, 0);
                int jb = j0 + mt * 16 + quad * 4;
                float2v z01, z23;
                z01.x = (jb + 0 > igi) ? c[0] : 0.f;
                z01.y = (jb + 1 > igi) ? c[1] : 0.f;
                z23.x = (jb + 2 > igi) ? c[2] : 0.f;
                z23.y = (jb + 3 > igi) ? c[3] : 0.f;
                float2v a01 = lrelu2(z01), a23 = lrelu2(z23);
                S2[n] += a01 + a23;
                Q2[n] = fma2(a01, a01, Q2[n]);
                Q2[n] = fma2(a23, a23, Q2[n]);
            }
        }
    };

    prefetch(ta, 0);
    if (!str) {
        for (int ii = 0; ii < 8; ii += 2) {
            prefetch(tb, ii + 1);
            bodyC(ta);
            if (ii + 2 < 8) prefetch(ta, ii + 2);
            bodyC(tb);
        }
    } else {
        for (int ii = 0; ii < 8; ii += 2) {
            prefetch(tb, ii + 1);
            bodyM(ii, ta);
            if (ii + 2 < 8) prefetch(ta, ii + 2);
            bodyM(ii + 1, tb);
        }
    }

    float* dst = SQe8 + (blockIdx.x & 7) * 256;
#pragma unroll
    for (int n = 0; n < 2; ++n) {
        float Sa = S2[n].x + S2[n].y;
        float Qa = Q2[n].x + Q2[n].y;
        Sa += __shfl_xor(Sa, 16); Sa += __shfl_xor(Sa, 32);
        Qa += __shfl_xor(Qa, 16); Qa += __shfl_xor(Qa, 32);
        if (quad == 0) {
            atomicAdd(&dst[w * 32 + n * 16 + col], Sa);
            atomicAdd(&dst[128 + w * 32 + n * 16 + col], Qa);
        }
    }
}

// ---------------- edge pass 2: probabilities + symmetric write ---------------
__global__ __launch_bounds__(256, 4) void edge_p2(
    const short* __restrict__ hb, const short* __restrict__ T,
    const float* __restrict__ b5, const float* __restrict__ w6d,
    const float* __restrict__ b6dp, float* __restrict__ out)
{
    int i0, j0; bool str;
    decode_tile(blockIdx.x, i0, j0, str);
    __shared__ float sV[4][8][64];    // per-wave partial h-sums (8 KB)
    __shared__ float sP[8][65];       // probs, padded (mirror transpose)

    int t = threadIdx.x, lane = t & 63, w = t >> 6;
    int quad = lane >> 4, col = lane & 15;

    float bb = b6dp[0];
    float b5q[2][4];
    float2v wq[2][2];                 // w6d at (m, r01/r23)
#pragma unroll
    for (int m = 0; m < 2; ++m)
#pragma unroll
        for (int r = 0; r < 4; ++r) {
            int h = w * 32 + m * 16 + quad * 4 + r;
            b5q[m][r] = b5[h];
            ((float*)&wq[m][r >> 1])[r & 1] = w6d[h];
        }

    short8 hfr[4][2];
#pragma unroll
    for (int mt = 0; mt < 4; ++mt)
#pragma unroll
        for (int ks = 0; ks < 2; ++ks)
            hfr[mt][ks] = *(const short8*)(hb + (size_t)(j0 + mt * 16 + col) * 64 + ks * 32 + quad * 8);

    const short* Tb = T + (size_t)i0 * 8192;
    int toff[2][2];
#pragma unroll
    for (int m = 0; m < 2; ++m)
#pragma unroll
        for (int ks = 0; ks < 2; ++ks)
            toff[m][ks] = ((((w * 2 + m) * 2 + ks) * 64) + lane) * 8;

    short8 ta[2][2], tb[2][2];

    auto prefetch = [&](short8 (&dst)[2][2], int i) {
        const short* Tn = Tb + (size_t)i * 8192;
#pragma unroll
        for (int m = 0; m < 2; ++m)
#pragma unroll
            for (int ks = 0; ks < 2; ++ks)
                dst[m][ks] = *(const short8*)(Tn + toff[m][ks]);
    };

    auto body2 = [&](int i, short8 (&tc)[2][2]) {
        float2v acc[4];
#pragma unroll
        for (int k = 0; k < 4; ++k) acc[k] = 0.f;
#pragma unroll
        for (int m = 0; m < 2; ++m) {
#pragma unroll
            for (int nj = 0; nj < 4; ++nj) {
                floatx4 c = {b5q[m][0], b5q[m][1], b5q[m][2], b5q[m][3]};
                c = __builtin_amdgcn_mfma_f32_16x16x32_bf16(tc[m][0], hfr[nj][0], c, 0, 0, 0);
                c = __builtin_amdgcn_mfma_f32_16x16x32_bf16(tc[m][1], hfr[nj][1], c, 0, 0, 0);
                float2v z01, z23;
                z01.x = c[0]; z01.y = c[1];
                z23.x = c[2]; z23.y = c[3];
                acc[nj] = fma2(lrelu2(z01), wq[m][0], acc[nj]);
                acc[nj] = fma2(lrelu2(z23), wq[m][1], acc[nj]);
            }
        }
        // per-i tail: quad-butterfly + single-writer plain store (no atomics)
#pragma unroll
        for (int nj = 0; nj < 4; ++nj) {
            float v = acc[nj].x + acc[nj].y;
            v += __shfl_xor(v, 16);
            v += __shfl_xor(v, 32);
            if (quad == 0) sV[w][i][nj * 16 + col] = v;
        }
    };

    prefetch(ta, 0);
    for (int ii = 0; ii < 8; ii += 2) {
        prefetch(tb, ii + 1);
        body2(ii, ta);
        if (ii + 2 < 8) prefetch(ta, ii + 2);
        body2(ii + 1, tb);
    }
    __syncthreads();

    // cross-wave sum + sigmoid + direct write (coalesced)
#pragma unroll
    for (int k = 0; k < 2; ++k) {
        int e = t + 256 * k;          // 0..511
        int il = e >> 6, jl = e & 63;
        float v = bb + sV[0][il][jl] + sV[1][il][jl] + sV[2][il][jl] + sV[3][il][jl];
        float p = 1.f / (1.f + __expf(-v));
        sP[il][jl] = p;
        int ig = i0 + il, jg = j0 + jl;
        float2v pr;
        if (!str || jg > ig) {
            pr.x = p; pr.y = 1.f - p;
            *(float2v*)(out + ((size_t)ig * NN + jg) * 2) = pr;
        } else if (jg == ig) {
            pr.x = 0.f; pr.y = 0.f;
            *(float2v*)(out + ((size_t)ig * NN + jg) * 2) = pr;
        }
    }
    __syncthreads();

    if (!str) {
        // mirror: 64 rows x 16 floats, float4 per thread
        int jr = t >> 2, f1 = (t & 3) * 4;
        float4 u;
#pragma unroll
        for (int e = 0; e < 4; ++e) {
            int ff = f1 + e;
            float p = sP[ff >> 1][jr];
            ((float*)&u)[e] = (ff & 1) ? 1.f - p : p;
        }
        *(float4*)(out + ((size_t)(j0 + jr) * NN + i0) * 2 + f1) = u;
    } else {
#pragma unroll
        for (int e = 0; e < 4; ++e) {     // mirror 64x8x2 = 1024 floats
            int f = t * 4 + e;
            int jr = f >> 4, ff = f & 15;
            int il = ff >> 1, c2 = ff & 1;
            int jg = j0 + jr, ig = i0 + il;
            if (jg > ig) {
                float p = sP[il][jr];
                out[((size_t)jg * NN + ig) * 2 + c2] = c2 ? 1.f - p : p;
            }
        }
    }
}

// ---------------------------------------------------------------------------
extern "C" void kernel_launch(void* const* d_in, const int* in_sizes, int n_in,
                              void* d_out, int out_size, void* d_ws, size_t ws_size,
                              hipStream_t stream) {
    const float* nf  = (const float*)d_in[1];   // d_in[0]=x unused (ref ignores it)
    const float* W1  = (const float*)d_in[2];
    const float* b1  = (const float*)d_in[3];
    const float* g1  = (const float*)d_in[4];
    const float* be1 = (const float*)d_in[5];
    const float* W2  = (const float*)d_in[6];
    const float* b2  = (const float*)d_in[7];
    const float* g2  = (const float*)d_in[8];
    const float* be2 = (const float*)d_in[9];
    const float* W3  = (const float*)d_in[10];
    const float* b3  = (const float*)d_in[11];
    const float* W5  = (const float*)d_in[12];
    const float* b5  = (const float*)d_in[13];
    const float* g5  = (const float*)d_in[14];
    const float* be5 = (const float*)d_in[15];
    const float* W6  = (const float*)d_in[16];
    const float* b6  = (const float*)d_in[17];
    float* out = (float*)d_out;

    float* wsf   = (float*)d_ws;
    float* stat1 = wsf;                 // 256
    float* stat2 = wsf + 256;           // 256
    float* SQe8  = wsf + 512;           // 8*256 = 2048 (per-XCD stat copies)
    float* w6d   = wsf + 2560;          // 128
    float* b6dp  = wsf + 2688;          // 1 (pad to 4096)
    float* act1  = wsf + 4096;          // 262144
    float* act2  = act1 + 262144;       // 262144
    short* hb    = (short*)(act2 + 262144);   // 131072 bf16
    short* w5bf  = hb + 131072;               // 8192 bf16
    short* Tbuf  = w5bf + 8192;               // 2048*8192 bf16 = 32 MB

    hipMemsetAsync(d_ws, 0, 4096 * sizeof(float), stream);

    k_l1<<<256, 256, 0, stream>>>(nf, W1, b1, W5, act1, stat1, w5bf);
    k_l2<<<256, 256, 0, stream>>>(act1, stat1, g1, be1, W2, b2, act2, stat2);
    k_l3<<<256, 256, 0, stream>>>(act2, stat2, g2, be2, W3, b3, nf, hb);
    k_bi<<<256, 256, 0, stream>>>(w5bf, hb, Tbuf);

    edge_p1<<<4224, 256, 0, stream>>>(hb, Tbuf, b5, SQe8);
    k_mid<<<1, 128, 0, stream>>>(SQe8, W6, b6, g5, be5, w6d, b6dp);
    edge_p2<<<4224, 256, 0, stream>>>(hb, Tbuf, b5, w6d, b6dp, out);
}